// Round 4
// baseline (596.941 us; speedup 1.0000x reference)
//
#include <hip/hip_runtime.h>
#include <hip/hip_bf16.h>
#include <stdint.h>

#define MDIM 8192
#define NDIM 4096
#define KDIM 4096

#define BM 128
#define BN 128
#define BK 64

#define XA_BLOCKS 512
#define CVT_BLOCKS 6144

typedef short bf16x8 __attribute__((ext_vector_type(8)));
typedef float floatx4 __attribute__((ext_vector_type(4)));

__device__ __forceinline__ unsigned short f2bf(float f) {
    union { __hip_bfloat16 h; unsigned short u; } v;
    v.h = __float2bfloat16(f);
    return v.u;
}

// ---------- fused pre-pass: ONE launch ----------
// blocks [0, XA_BLOCKS):          xa[m,r] = (1/16) * sum_k x_fp32[m,k]*A[r,k]
//                                 (reads ORIGINAL fp32 x -> no dependency on cvt)
// blocks [XA_BLOCKS, XA_BLOCKS+CVT_BLOCKS): grid-stride fp32->bf16 of x, W, B
__global__ __launch_bounds__(256) void fused_pre(
    const float* __restrict__ x,    // [M,K] fp32
    const float* __restrict__ Wf,   // [N,K] fp32
    const float* __restrict__ Bf,   // [N,16] fp32
    const float* __restrict__ A,    // [16,K] fp32
    unsigned short* __restrict__ xc,  // [M,K] bf16 out
    unsigned short* __restrict__ Wc,  // [N,K] bf16 out
    unsigned short* __restrict__ Bc,  // [N,16] bf16 out
    unsigned short* __restrict__ xa) {// [M,16] bf16 out (prescaled)
    const int b = blockIdx.x;

    if (b < XA_BLOCKS) {
        // ---- xa path: one wave handles 4 rows of x ----
        const int lane = threadIdx.x & 63;
        const int wave = (b * 256 + (int)threadIdx.x) >> 6;   // [0, 2048)
        const int m0 = wave * 4;

        float acc[4][16];
#pragma unroll
        for (int q = 0; q < 4; ++q)
#pragma unroll
            for (int r = 0; r < 16; ++r) acc[q][r] = 0.f;

        for (int k = lane * 4; k < KDIM; k += 256) {
            float4 xv[4];
#pragma unroll
            for (int q = 0; q < 4; ++q)
                xv[q] = *(const float4*)(x + (size_t)(m0 + q) * KDIM + k);
#pragma unroll
            for (int r = 0; r < 16; ++r) {
                float4 av = *(const float4*)(A + (size_t)r * KDIM + k);
#pragma unroll
                for (int q = 0; q < 4; ++q)
                    acc[q][r] += xv[q].x * av.x + xv[q].y * av.y +
                                 xv[q].z * av.z + xv[q].w * av.w;
            }
        }
#pragma unroll
        for (int q = 0; q < 4; ++q)
#pragma unroll
            for (int r = 0; r < 16; ++r) {
#pragma unroll
                for (int off = 32; off > 0; off >>= 1)
                    acc[q][r] += __shfl_xor(acc[q][r], off, 64);
            }
        if (lane == 0) {
            const float scale = 1.0f / 16.0f;
#pragma unroll
            for (int q = 0; q < 4; ++q)
#pragma unroll
                for (int r = 0; r < 16; ++r)
                    xa[(size_t)(m0 + q) * 16 + r] = f2bf(acc[q][r] * scale);
        }
        return;
    }

    // ---- cvt path: grid-stride over x (4194304 chunks), W (2097152), B (8192) ----
    const int NX = (MDIM * KDIM) / 8;
    const int NW = (NDIM * KDIM) / 8;
    const int NB = (NDIM * 16) / 8;
    const int total = NX + NW + NB;
    int idx = (b - XA_BLOCKS) * 256 + (int)threadIdx.x;
    const int stride = CVT_BLOCKS * 256;
    for (int i = idx; i < total; i += stride) {
        const float* src;
        unsigned short* dst;
        int off;
        if (i < NX)           { src = x;  dst = xc; off = i; }
        else if (i < NX + NW) { src = Wf; dst = Wc; off = i - NX; }
        else                  { src = Bf; dst = Bc; off = i - NX - NW; }
        const float4* p = (const float4*)src + (size_t)off * 2;
        float4 a = p[0], c = p[1];
        bf16x8 o;
        o[0] = (short)f2bf(a.x); o[1] = (short)f2bf(a.y);
        o[2] = (short)f2bf(a.z); o[3] = (short)f2bf(a.w);
        o[4] = (short)f2bf(c.x); o[5] = (short)f2bf(c.y);
        o[6] = (short)f2bf(c.z); o[7] = (short)f2bf(c.w);
        *((bf16x8*)dst + off) = o;
    }
}

// ---------- 128x128 bf16 GEMM, XOR-swizzled LDS, fused LoRA + bias ----------
// (r0 proven kernel: 250 us, MfmaUtil 55%, VGPR 64, 0 bank conflicts)
// + XCD-aware workgroup swizzle: 2048 wgs, 256 per XCD contiguous (bijective,
//   2048 % 8 == 0). XCD c covers bm rows [8c, 8c+8) -> A-panel L2 reuse.
// LDS slot layout: 16B chunk (row, cc) of a tile lives at slot row*8 + (cc ^ (row&7)).
// Staging keeps the DMA dest (wave-uniform base + lane*16) and permutes the SOURCE.
__global__ __launch_bounds__(256, 4) void lora_gemm(
    const unsigned short* __restrict__ x,   // [M,K] bf16
    const unsigned short* __restrict__ W,   // [N,K] bf16
    const float* __restrict__ bias,         // [N] fp32
    const unsigned short* __restrict__ Bl,  // [N,16] bf16
    const unsigned short* __restrict__ xa,  // [M,16] bf16 (prescaled)
    float* __restrict__ out) {              // [M,N] fp32
    __shared__ __align__(16) unsigned short lA[BM * BK];
    __shared__ __align__(16) unsigned short lB[BN * BK];

    int id = blockIdx.y * 32 + blockIdx.x;      // dispatch-linear id [0,2048)
    id = (id & 7) * 256 + (id >> 3);            // XCD-contiguous remap
    const int bn = (id & 31) * BN;
    const int bm = (id >> 5) * BM;

    const int t = threadIdx.x;
    const int lane = t & 63;
    const int wave = t >> 6;
    const int wm = (wave >> 1) * 64;
    const int wn = (wave & 1) * 64;
    const int fr = lane & 15;
    const int fq = lane >> 4;
    const int f7 = fr & 7;

    // Per-lane source permutation for swizzled staging:
    const int srow = lane >> 3;                    // row-within-8 of this lane's slot
    const int scc = (lane & 7) ^ srow;             // swizzled k-chunk to fetch

    floatx4 acc[4][4];
#pragma unroll
    for (int i = 0; i < 4; ++i)
#pragma unroll
        for (int j = 0; j < 4; ++j)
            acc[i][j] = (floatx4){0.f, 0.f, 0.f, 0.f};

    // LoRA delta first: one rank-16 MFMA step, fragments direct from global,
    // zero-padded to K=32 in registers (fq>=2 lanes hold zeros).
    {
        bf16x8 z = {0, 0, 0, 0, 0, 0, 0, 0};
        bf16x8 af[4], bfv[4];
#pragma unroll
        for (int i = 0; i < 4; ++i) {
            int row = bm + wm + i * 16 + fr;
            af[i] = (fq < 2) ? *(const bf16x8*)(xa + (size_t)row * 16 + fq * 8) : z;
        }
#pragma unroll
        for (int j = 0; j < 4; ++j) {
            int row = bn + wn + j * 16 + fr;
            bfv[j] = (fq < 2) ? *(const bf16x8*)(Bl + (size_t)row * 16 + fq * 8) : z;
        }
#pragma unroll
        for (int i = 0; i < 4; ++i)
#pragma unroll
            for (int j = 0; j < 4; ++j)
                acc[i][j] = __builtin_amdgcn_mfma_f32_16x16x32_bf16(af[i], bfv[j], acc[i][j], 0, 0, 0);
    }

    for (int k0 = 0; k0 < KDIM; k0 += BK) {
#pragma unroll
        for (int i = 0; i < 4; ++i) {
            int cbase = i * 256 + wave * 64;           // slot base (wave-uniform)
            int row = (cbase >> 3) + srow;             // this lane's tile row
            __builtin_amdgcn_global_load_lds(
                (const __attribute__((address_space(1))) unsigned int*)(x + (size_t)(bm + row) * KDIM + k0 + scc * 8),
                (__attribute__((address_space(3))) unsigned int*)&lA[cbase * 8], 16, 0, 0);
            __builtin_amdgcn_global_load_lds(
                (const __attribute__((address_space(1))) unsigned int*)(W + (size_t)(bn + row) * KDIM + k0 + scc * 8),
                (__attribute__((address_space(3))) unsigned int*)&lB[cbase * 8], 16, 0, 0);
        }
        __syncthreads();

#pragma unroll
        for (int kk = 0; kk < BK; kk += 32) {
            const int jb = kk >> 3;                    // base chunk index (0 or 4)
            bf16x8 af[4], bfv[4];
#pragma unroll
            for (int i = 0; i < 4; ++i) {
                int r = wm + i * 16 + fr;
                af[i] = *(const bf16x8*)&lA[r * BK + (((jb + fq) ^ f7) << 3)];
            }
#pragma unroll
            for (int j = 0; j < 4; ++j) {
                int r = wn + j * 16 + fr;
                bfv[j] = *(const bf16x8*)&lB[r * BK + (((jb + fq) ^ f7) << 3)];
            }
#pragma unroll
            for (int i = 0; i < 4; ++i)
#pragma unroll
                for (int j = 0; j < 4; ++j)
                    acc[i][j] = __builtin_amdgcn_mfma_f32_16x16x32_bf16(af[i], bfv[j], acc[i][j], 0, 0, 0);
        }
        __syncthreads();
    }

    // Epilogue: D layout col=lane&15, row=(lane>>4)*4+reg. Add fp32 bias, store fp32.
#pragma unroll
    for (int j = 0; j < 4; ++j) {
        int col = bn + wn + j * 16 + fr;
        float bv = bias[col];
#pragma unroll
        for (int i = 0; i < 4; ++i) {
            int row0 = bm + wm + i * 16 + fq * 4;
#pragma unroll
            for (int r = 0; r < 4; ++r) {
                out[(size_t)(row0 + r) * NDIM + col] = acc[i][j][r] + bv;
            }
        }
    }
}

extern "C" void kernel_launch(void* const* d_in, const int* in_sizes, int n_in,
                              void* d_out, int out_size, void* d_ws, size_t ws_size,
                              hipStream_t stream) {
    const float* x    = (const float*)d_in[0];  // [4,2048,4096] fp32
    const float* W    = (const float*)d_in[1];  // [4096,4096] fp32
    const float* bias = (const float*)d_in[2];  // [4096] fp32
    const float* A    = (const float*)d_in[3];  // [16,4096] fp32
    const float* Bf   = (const float*)d_in[4];  // [4096,16] fp32
    float* out = (float*)d_out;                 // [8192,4096] fp32

    unsigned short* xc = (unsigned short*)d_ws;              // 64 MB
    unsigned short* Wc = xc + (size_t)MDIM * KDIM;           // 32 MB
    unsigned short* xa = Wc + (size_t)NDIM * KDIM;           // 256 KB
    unsigned short* Bc = xa + (size_t)MDIM * 16;             // 128 KB

    fused_pre<<<XA_BLOCKS + CVT_BLOCKS, 256, 0, stream>>>(x, W, Bf, A, xc, Wc, Bc, xa);
    lora_gemm<<<dim3(NDIM / BN, MDIM / BM), 256, 0, stream>>>(xc, Wc, bias, Bc, xa, out);
}

// Round 6
// 531.810 us; speedup vs baseline: 1.1225x; 1.1225x over previous
//
#include <hip/hip_runtime.h>
#include <hip/hip_bf16.h>
#include <stdint.h>

#define MDIM 8192
#define NDIM 4096
#define KDIM 4096

#define BM 128
#define BN 128
#define BK 64

#define XA_BLOCKS 512
#define CVT_BLOCKS 4096

typedef short bf16x8 __attribute__((ext_vector_type(8)));
typedef float floatx4 __attribute__((ext_vector_type(4)));

__device__ __forceinline__ unsigned short f2bf(float f) {
    union { __hip_bfloat16 h; unsigned short u; } v;
    v.h = __float2bfloat16(f);
    return v.u;
}

// ---------- fused pre-pass: ONE launch, x read exactly once ----------
// blocks [0, XA_BLOCKS): xa[m,r] = (1/16)*sum_k x_fp32[m,k]*A[r,k]  AND
//                        xc[m,k] = bf16(x[m,k])  (same float4s, zero extra reads)
// blocks [XA_BLOCKS, ...): grid-stride fp32->bf16 of W and B only.
__global__ __launch_bounds__(256) void fused_pre(
    const float* __restrict__ x,    // [M,K] fp32
    const float* __restrict__ Wf,   // [N,K] fp32
    const float* __restrict__ Bf,   // [N,16] fp32
    const float* __restrict__ A,    // [16,K] fp32
    unsigned short* __restrict__ xc,  // [M,K] bf16 out
    unsigned short* __restrict__ Wc,  // [N,K] bf16 out
    unsigned short* __restrict__ Bc,  // [N,16] bf16 out
    unsigned short* __restrict__ xa) {// [M,16] bf16 out (prescaled)
    const int b = blockIdx.x;

    if (b < XA_BLOCKS) {
        // ---- xa + xc path: one wave handles 4 rows of x ----
        const int lane = threadIdx.x & 63;
        const int wave = (b * 256 + (int)threadIdx.x) >> 6;   // [0, 2048)
        const int m0 = wave * 4;

        float acc[4][16];
#pragma unroll
        for (int q = 0; q < 4; ++q)
#pragma unroll
            for (int r = 0; r < 16; ++r) acc[q][r] = 0.f;

        for (int k = lane * 4; k < KDIM; k += 256) {
            float4 xv[4];
#pragma unroll
            for (int q = 0; q < 4; ++q) {
                xv[q] = *(const float4*)(x + (size_t)(m0 + q) * KDIM + k);
                short4 o;
                o.x = (short)f2bf(xv[q].x); o.y = (short)f2bf(xv[q].y);
                o.z = (short)f2bf(xv[q].z); o.w = (short)f2bf(xv[q].w);
                *(short4*)(xc + (size_t)(m0 + q) * KDIM + k) = o;
            }
#pragma unroll
            for (int r = 0; r < 16; ++r) {
                float4 av = *(const float4*)(A + (size_t)r * KDIM + k);
#pragma unroll
                for (int q = 0; q < 4; ++q)
                    acc[q][r] += xv[q].x * av.x + xv[q].y * av.y +
                                 xv[q].z * av.z + xv[q].w * av.w;
            }
        }
#pragma unroll
        for (int q = 0; q < 4; ++q)
#pragma unroll
            for (int r = 0; r < 16; ++r) {
#pragma unroll
                for (int off = 32; off > 0; off >>= 1)
                    acc[q][r] += __shfl_xor(acc[q][r], off, 64);
            }
        if (lane == 0) {
            const float scale = 1.0f / 16.0f;
#pragma unroll
            for (int q = 0; q < 4; ++q)
#pragma unroll
                for (int r = 0; r < 16; ++r)
                    xa[(size_t)(m0 + q) * 16 + r] = f2bf(acc[q][r] * scale);
        }
        return;
    }

    // ---- cvt path: grid-stride over W (2097152 chunks) + B (8192 chunks) ----
    const int NW = (NDIM * KDIM) / 8;
    const int NB = (NDIM * 16) / 8;
    const int total = NW + NB;
    int idx = (b - XA_BLOCKS) * 256 + (int)threadIdx.x;
    const int stride = CVT_BLOCKS * 256;
    for (int i = idx; i < total; i += stride) {
        const float* src;
        unsigned short* dst;
        int off;
        if (i < NW) { src = Wf; dst = Wc; off = i; }
        else        { src = Bf; dst = Bc; off = i - NW; }
        const float4* p = (const float4*)src + (size_t)off * 2;
        float4 a = p[0], c = p[1];
        bf16x8 o;
        o[0] = (short)f2bf(a.x); o[1] = (short)f2bf(a.y);
        o[2] = (short)f2bf(a.z); o[3] = (short)f2bf(a.w);
        o[4] = (short)f2bf(c.x); o[5] = (short)f2bf(c.y);
        o[6] = (short)f2bf(c.z); o[7] = (short)f2bf(c.w);
        *((bf16x8*)dst + off) = o;
    }
}

// ---------- 128x128 bf16 GEMM, XOR-swizzled LDS, fused LoRA + bias ----------
// EXACT r0 kernel (250 us, MfmaUtil 55%, FETCH 378 MB, 0 bank conflicts).
// NO workgroup remap: with gridDim.x=32, the natural dispatch order stripes
// bn-columns mod-8 across XCDs -> 4 B-panels (4 MB) resident per XCD L2,
// reused across all bm rows. (r4's contiguous-band remap broke this: FETCH
// 378->900 MB, dur 250->326 us. Measured, do not re-add.)
// LDS slot layout: 16B chunk (row, cc) of a tile lives at slot row*8 + (cc ^ (row&7)).
// Staging keeps the DMA dest (wave-uniform base + lane*16) and permutes the SOURCE.
__global__ __launch_bounds__(256, 4) void lora_gemm(
    const unsigned short* __restrict__ x,   // [M,K] bf16
    const unsigned short* __restrict__ W,   // [N,K] bf16
    const float* __restrict__ bias,         // [N] fp32
    const unsigned short* __restrict__ Bl,  // [N,16] bf16
    const unsigned short* __restrict__ xa,  // [M,16] bf16 (prescaled)
    float* __restrict__ out) {              // [M,N] fp32
    __shared__ __align__(16) unsigned short lA[BM * BK];
    __shared__ __align__(16) unsigned short lB[BN * BK];

    const int bn = blockIdx.x * BN;
    const int bm = blockIdx.y * BM;
    const int t = threadIdx.x;
    const int lane = t & 63;
    const int wave = t >> 6;
    const int wm = (wave >> 1) * 64;
    const int wn = (wave & 1) * 64;
    const int fr = lane & 15;
    const int fq = lane >> 4;
    const int f7 = fr & 7;

    // Per-lane source permutation for swizzled staging:
    const int srow = lane >> 3;                    // row-within-8 of this lane's slot
    const int scc = (lane & 7) ^ srow;             // swizzled k-chunk to fetch

    floatx4 acc[4][4];
#pragma unroll
    for (int i = 0; i < 4; ++i)
#pragma unroll
        for (int j = 0; j < 4; ++j)
            acc[i][j] = (floatx4){0.f, 0.f, 0.f, 0.f};

    // LoRA delta first: one rank-16 MFMA step, fragments direct from global,
    // zero-padded to K=32 in registers (fq>=2 lanes hold zeros).
    {
        bf16x8 z = {0, 0, 0, 0, 0, 0, 0, 0};
        bf16x8 af[4], bfv[4];
#pragma unroll
        for (int i = 0; i < 4; ++i) {
            int row = bm + wm + i * 16 + fr;
            af[i] = (fq < 2) ? *(const bf16x8*)(xa + (size_t)row * 16 + fq * 8) : z;
        }
#pragma unroll
        for (int j = 0; j < 4; ++j) {
            int row = bn + wn + j * 16 + fr;
            bfv[j] = (fq < 2) ? *(const bf16x8*)(Bl + (size_t)row * 16 + fq * 8) : z;
        }
#pragma unroll
        for (int i = 0; i < 4; ++i)
#pragma unroll
            for (int j = 0; j < 4; ++j)
                acc[i][j] = __builtin_amdgcn_mfma_f32_16x16x32_bf16(af[i], bfv[j], acc[i][j], 0, 0, 0);
    }

    for (int k0 = 0; k0 < KDIM; k0 += BK) {
#pragma unroll
        for (int i = 0; i < 4; ++i) {
            int cbase = i * 256 + wave * 64;           // slot base (wave-uniform)
            int row = (cbase >> 3) + srow;             // this lane's tile row
            __builtin_amdgcn_global_load_lds(
                (const __attribute__((address_space(1))) unsigned int*)(x + (size_t)(bm + row) * KDIM + k0 + scc * 8),
                (__attribute__((address_space(3))) unsigned int*)&lA[cbase * 8], 16, 0, 0);
            __builtin_amdgcn_global_load_lds(
                (const __attribute__((address_space(1))) unsigned int*)(W + (size_t)(bn + row) * KDIM + k0 + scc * 8),
                (__attribute__((address_space(3))) unsigned int*)&lB[cbase * 8], 16, 0, 0);
        }
        __syncthreads();

#pragma unroll
        for (int kk = 0; kk < BK; kk += 32) {
            const int jb = kk >> 3;                    // base chunk index (0 or 4)
            bf16x8 af[4], bfv[4];
#pragma unroll
            for (int i = 0; i < 4; ++i) {
                int r = wm + i * 16 + fr;
                af[i] = *(const bf16x8*)&lA[r * BK + (((jb + fq) ^ f7) << 3)];
            }
#pragma unroll
            for (int j = 0; j < 4; ++j) {
                int r = wn + j * 16 + fr;
                bfv[j] = *(const bf16x8*)&lB[r * BK + (((jb + fq) ^ f7) << 3)];
            }
#pragma unroll
            for (int i = 0; i < 4; ++i)
#pragma unroll
                for (int j = 0; j < 4; ++j)
                    acc[i][j] = __builtin_amdgcn_mfma_f32_16x16x32_bf16(af[i], bfv[j], acc[i][j], 0, 0, 0);
        }
        __syncthreads();
    }

    // Epilogue: D layout col=lane&15, row=(lane>>4)*4+reg. Add fp32 bias, store fp32.
#pragma unroll
    for (int j = 0; j < 4; ++j) {
        int col = bn + wn + j * 16 + fr;
        float bv = bias[col];
#pragma unroll
        for (int i = 0; i < 4; ++i) {
            int row0 = bm + wm + i * 16 + fq * 4;
#pragma unroll
            for (int r = 0; r < 4; ++r) {
                out[(size_t)(row0 + r) * NDIM + col] = acc[i][j][r] + bv;
            }
        }
    }
}

extern "C" void kernel_launch(void* const* d_in, const int* in_sizes, int n_in,
                              void* d_out, int out_size, void* d_ws, size_t ws_size,
                              hipStream_t stream) {
    const float* x    = (const float*)d_in[0];  // [4,2048,4096] fp32
    const float* W    = (const float*)d_in[1];  // [4096,4096] fp32
    const float* bias = (const float*)d_in[2];  // [4096] fp32
    const float* A    = (const float*)d_in[3];  // [16,4096] fp32
    const float* Bf   = (const float*)d_in[4];  // [4096,16] fp32
    float* out = (float*)d_out;                 // [8192,4096] fp32

    unsigned short* xc = (unsigned short*)d_ws;              // 64 MB
    unsigned short* Wc = xc + (size_t)MDIM * KDIM;           // 32 MB
    unsigned short* xa = Wc + (size_t)NDIM * KDIM;           // 256 KB
    unsigned short* Bc = xa + (size_t)MDIM * 16;             // 128 KB

    fused_pre<<<XA_BLOCKS + CVT_BLOCKS, 256, 0, stream>>>(x, W, Bf, A, xc, Wc, Bc, xa);
    lora_gemm<<<dim3(NDIM / BN, MDIM / BM), 256, 0, stream>>>(xc, Wc, bias, Bc, xa, out);
}